// Round 1
// baseline (125.206 us; speedup 1.0000x reference)
//
#include <hip/hip_runtime.h>
#include <hip/hip_bf16.h>
#include <stdint.h>

typedef __attribute__((ext_vector_type(4))) float  floatx4;
typedef __attribute__((ext_vector_type(2))) float  floatx2;
typedef __attribute__((ext_vector_type(8))) __bf16 bf16x8;

#define FP8_MAX 448.0f

// HW OCP e4m3fn round-trip (RNE), matches ml_dtypes float8_e4m3fn for |v|<=448
__device__ __forceinline__ floatx2 fp8_qdq2(float a, float b) {
    int p = __builtin_amdgcn_cvt_pk_fp8_f32(a, b, 0, false);
    return __builtin_amdgcn_cvt_pk_f32_fp8(p, false);
}

__device__ __forceinline__ unsigned short f2bf(float f) {
    __hip_bfloat16 h = __float2bfloat16(f);
    union { __hip_bfloat16 h; unsigned short u; } cv;
    cv.h = h;
    return cv.u;
}

__device__ __forceinline__ void async_copy16(void* lds, const void* g) {
    __builtin_amdgcn_global_load_lds(
        (const __attribute__((address_space(1))) unsigned int*)g,
        (__attribute__((address_space(3))) unsigned int*)lds,
        16, 0, 0);
}

// ---------------------------------------------------------------------------
// Kernel 1: dequantize W [D=512][F=512] (quant blocks of 128 along F),
//           write transposed bf16 Wt [F=512][D=512].
// One block of 128 threads per row d. Thread t owns f = 4t..4t+3, so the
// 32-thread group [32*fb, 32*fb+32) covers exactly one 128-wide quant block.
__global__ void wdq_kernel(const float* __restrict__ W,
                           __hip_bfloat16* __restrict__ Wt) {
    const int D = 512, F = 512;
    int d = blockIdx.x;
    int t = threadIdx.x;
    float4 v = *reinterpret_cast<const float4*>(W + (size_t)d * F + t * 4);
    float am = fmaxf(fmaxf(fabsf(v.x), fabsf(v.y)), fmaxf(fabsf(v.z), fabsf(v.w)));
#pragma unroll
    for (int s = 16; s >= 1; s >>= 1) am = fmaxf(am, __shfl_xor(am, s));
    float scale = fmaxf(am, 1e-4f) / FP8_MAX;   // IEEE div, matches reference
    floatx2 d01 = fp8_qdq2(v.x / scale, v.y / scale);
    floatx2 d23 = fp8_qdq2(v.z / scale, v.w / scale);
    int f0 = t * 4;
    Wt[(size_t)(f0 + 0) * D + d] = __float2bfloat16(d01[0] * scale);
    Wt[(size_t)(f0 + 1) * D + d] = __float2bfloat16(d01[1] * scale);
    Wt[(size_t)(f0 + 2) * D + d] = __float2bfloat16(d23[0] * scale);
    Wt[(size_t)(f0 + 3) * D + d] = __float2bfloat16(d23[1] * scale);
}

// ---------------------------------------------------------------------------
// Kernel 2: quant-dequant X [M][512] f32 -> bf16 (quant blocks of 128 along K).
// One block (256 thr = 4 waves) per row; wave w owns quant block w (128 elems,
// 2 per lane), full-wave shuffle amax.
__global__ void xqdq_kernel(const float* __restrict__ X,
                            __hip_bfloat16* __restrict__ Xdq) {
    const int K = 512;
    size_t m = blockIdx.x;
    int w = threadIdx.x >> 6;
    int l = threadIdx.x & 63;
    size_t base = m * K + (size_t)w * 128 + l * 2;
    float2 v = *reinterpret_cast<const float2*>(X + base);
    float am = fmaxf(fabsf(v.x), fabsf(v.y));
#pragma unroll
    for (int s = 32; s >= 1; s >>= 1) am = fmaxf(am, __shfl_xor(am, s));
    float scale = fmaxf(am, 1e-4f) / FP8_MAX;
    floatx2 dq = fp8_qdq2(v.x / scale, v.y / scale);
    unsigned int packed = (unsigned int)f2bf(dq[0] * scale)
                        | ((unsigned int)f2bf(dq[1] * scale) << 16);
    *reinterpret_cast<unsigned int*>(Xdq + base) = packed;
}

// ---------------------------------------------------------------------------
// Kernel 3: bf16 GEMM  C[M][512] = A[M][512] * Bt[512][512]^T + bias
// m97-style: 128x128 tile, BK=64, 4 waves (2x2), 16x16x32 MFMA,
// global_load_lds width-16 staging, 2 barriers per K-step.
#define BM 128
#define BN 128
#define BK 64

__global__ __launch_bounds__(256, 2) void gemm_kernel(
        const __hip_bfloat16* __restrict__ A,   // [M][K] row-major
        const __hip_bfloat16* __restrict__ Bt,  // [N][K] row-major (B^T)
        const float* __restrict__ bias,         // [N]
        float* __restrict__ C, int M) {
    const int K = 512, N = 512;
    __shared__ __hip_bfloat16 As[BM][BK];   // 16 KB
    __shared__ __hip_bfloat16 Bs[BN][BK];   // 16 KB

    int bx = blockIdx.x;
    int tN = bx & 3;          // N/BN = 4; consecutive blocks share the A panel
    int tM = bx >> 2;
    int wid  = threadIdx.x >> 6;
    int lane = threadIdx.x & 63;
    int wr = wid >> 1, wc = wid & 1;

    const __hip_bfloat16* Ab = A  + (size_t)tM * BM * K;
    const __hip_bfloat16* Bb = Bt + (size_t)tN * BN * K;

    floatx4 acc[4][4] = {};

    int lrow = lane >> 3;        // 0..7 (row within 8-row chunk)
    int lcol = (lane & 7) * 8;   // element col within BK

    for (int k0 = 0; k0 < K; k0 += BK) {
#pragma unroll
        for (int c = 0; c < 4; ++c) {
            int ch  = wid * 4 + c;       // 16 chunks of 1 KB each
            int row = ch * 8 + lrow;
            async_copy16((char*)&As[0][0] + ch * 1024,
                         Ab + (size_t)row * K + k0 + lcol);
            async_copy16((char*)&Bs[0][0] + ch * 1024,
                         Bb + (size_t)row * K + k0 + lcol);
        }
        __syncthreads();   // drains vmcnt (compiler emits the waitcnt)

#pragma unroll
        for (int ks = 0; ks < 2; ++ks) {
            bf16x8 a[4], b[4];
#pragma unroll
            for (int i = 0; i < 4; ++i) {
                a[i] = *reinterpret_cast<const bf16x8*>(
                    &As[wr * 64 + i * 16 + (lane & 15)][ks * 32 + (lane >> 4) * 8]);
                b[i] = *reinterpret_cast<const bf16x8*>(
                    &Bs[wc * 64 + i * 16 + (lane & 15)][ks * 32 + (lane >> 4) * 8]);
            }
#pragma unroll
            for (int mi = 0; mi < 4; ++mi)
#pragma unroll
                for (int ni = 0; ni < 4; ++ni)
                    acc[mi][ni] = __builtin_amdgcn_mfma_f32_16x16x32_bf16(
                        a[mi], b[ni], acc[mi][ni], 0, 0, 0);
        }
        __syncthreads();
    }

    // Epilogue: C/D layout col = lane&15, row = (lane>>4)*4 + i  (m89/m91)
    int colbase = tN * BN + wc * 64 + (lane & 15);
    int rowbase = tM * BM + wr * 64 + (lane >> 4) * 4;
#pragma unroll
    for (int mi = 0; mi < 4; ++mi) {
#pragma unroll
        for (int ni = 0; ni < 4; ++ni) {
            int col = colbase + ni * 16;
            float bv = bias[col];
            int r0 = rowbase + mi * 16;
#pragma unroll
            for (int i = 0; i < 4; ++i)
                C[(size_t)(r0 + i) * N + col] = acc[mi][ni][i] + bv;
        }
    }
}

// ---------------------------------------------------------------------------
extern "C" void kernel_launch(void* const* d_in, const int* in_sizes, int n_in,
                              void* d_out, int out_size, void* d_ws, size_t ws_size,
                              hipStream_t stream) {
    const float* X    = (const float*)d_in[0];
    const float* W    = (const float*)d_in[1];
    const float* bias = (const float*)d_in[2];
    const int K = 512;
    const int M = in_sizes[0] / K;   // 65536

    __hip_bfloat16* Wt  = (__hip_bfloat16*)d_ws;          // 512*512*2 = 512 KB
    __hip_bfloat16* Xdq = Wt + 512 * 512;                 // M*512*2   = 64 MB

    wdq_kernel<<<dim3(512), dim3(128), 0, stream>>>(W, Wt);
    xqdq_kernel<<<dim3(M), dim3(256), 0, stream>>>(X, Xdq);
    gemm_kernel<<<dim3((M / BM) * (512 / BN)), dim3(256), 0, stream>>>(
        Xdq, Wt, bias, (float*)d_out, M);
}

// Round 2
// 104.483 us; speedup vs baseline: 1.1983x; 1.1983x over previous
//
#include <hip/hip_runtime.h>
#include <hip/hip_bf16.h>

typedef __attribute__((ext_vector_type(4))) float  floatx4;
typedef __attribute__((ext_vector_type(2))) float  floatx2;
typedef __attribute__((ext_vector_type(8))) __bf16 bf16x8;

#define FP8_MAX 448.0f

// HW OCP e4m3fn round-trip (RNE), matches ml_dtypes float8_e4m3fn for |v|<=448
__device__ __forceinline__ floatx2 fp8_qdq2(float a, float b) {
    int p = __builtin_amdgcn_cvt_pk_fp8_f32(a, b, 0, false);
    return __builtin_amdgcn_cvt_pk_f32_fp8(p, false);
}

__device__ __forceinline__ unsigned int f2bf(float f) {
    union { __hip_bfloat16 h; unsigned short u; } cv;
    cv.h = __float2bfloat16(f);
    return (unsigned int)cv.u;
}

__device__ __forceinline__ void async_copy16(void* lds, const void* g) {
    __builtin_amdgcn_global_load_lds(
        (const __attribute__((address_space(1))) unsigned int*)g,
        (__attribute__((address_space(3))) unsigned int*)lds,
        16, 0, 0);
}

// ---------------------------------------------------------------------------
// Kernel 1: dequantize W [D=512][F=512] (quant blocks of 128 along F),
//           write transposed bf16 Wt [F=512][D=512]. (unchanged, ~3 us)
__global__ void wdq_kernel(const float* __restrict__ W,
                           __hip_bfloat16* __restrict__ Wt) {
    const int D = 512, F = 512;
    int d = blockIdx.x;
    int t = threadIdx.x;
    float4 v = *reinterpret_cast<const float4*>(W + (size_t)d * F + t * 4);
    float am = fmaxf(fmaxf(fabsf(v.x), fabsf(v.y)), fmaxf(fabsf(v.z), fabsf(v.w)));
#pragma unroll
    for (int s = 16; s >= 1; s >>= 1) am = fmaxf(am, __shfl_xor(am, s));
    float scale = fmaxf(am, 1e-4f) / FP8_MAX;   // IEEE div, matches reference
    floatx2 d01 = fp8_qdq2(v.x / scale, v.y / scale);
    floatx2 d23 = fp8_qdq2(v.z / scale, v.w / scale);
    int f0 = t * 4;
    Wt[(size_t)(f0 + 0) * D + d] = __float2bfloat16(d01[0] * scale);
    Wt[(size_t)(f0 + 1) * D + d] = __float2bfloat16(d01[1] * scale);
    Wt[(size_t)(f0 + 2) * D + d] = __float2bfloat16(d23[0] * scale);
    Wt[(size_t)(f0 + 3) * D + d] = __float2bfloat16(d23[1] * scale);
}

// ---------------------------------------------------------------------------
// Kernel 2 (fused): quantize X on the fly + bf16 GEMM + bias.
//   C[M][512] = qdq(X)[M][512] * Wt[512][512]^T + bias
// BM=64, BN=256, BK=128 (== quant block), 256 threads = 4 waves, wave-grid 1x4.
// LDS 48KB static: As bf16[64][128] (reg-staged fused quant) +
//                  Bs bf16[256][64] (global_load_lds, two 64-k halves).
#define BM 64
#define BN 256
#define BK 128

__global__ __launch_bounds__(256, 3) void fused_gemm(
        const float* __restrict__ X,             // [M][512] f32
        const __hip_bfloat16* __restrict__ Wt,   // [512 f][512 k] bf16
        const float* __restrict__ bias,          // [512]
        float* __restrict__ C, int M) {
    const int K = 512, N = 512;
    __shared__ __hip_bfloat16 As[BM][BK];   // 16 KB
    __shared__ __hip_bfloat16 Bs[BN][64];   // 32 KB

    int bx   = blockIdx.x;
    int tN   = bx & 1;            // 512/BN = 2
    int tM   = bx >> 1;
    int tid  = threadIdx.x;
    int wid  = tid >> 6;
    int lane = tid & 63;

    const float* Xb = X + (size_t)tM * BM * K;
    const __hip_bfloat16* Wb = Wt + (size_t)tN * BN * K;

    // A-quant mapping: 4 threads per row, 32 floats each (one 128-k quant block)
    int ar = tid >> 2;            // row 0..63
    int aq = tid & 3;             // quarter

    floatx4 acc[4][4] = {};

    for (int kt = 0; kt < K / BK; ++kt) {
        const int k0 = kt * BK;

        // ---- stage B half 0 (async DMA; overlaps A quant VALU below) ----
#pragma unroll
        for (int c = 0; c < 8; ++c) {
            int chunk = wid * 8 + c;                 // 32 x 1KB chunks
            int frow  = chunk * 8 + (lane >> 3);     // 8 rows of 128B per chunk
            async_copy16((char*)&Bs[0][0] + chunk * 1024,
                         (const char*)(Wb + (size_t)frow * K + k0) + (lane & 7) * 16);
        }

        // ---- A: load f32, blockwise fp8 quant-dequant, write bf16 to LDS ----
        float4 v[8];
        const float* src = Xb + (size_t)ar * K + k0 + aq * 32;
#pragma unroll
        for (int j = 0; j < 8; ++j)
            v[j] = *reinterpret_cast<const float4*>(src + j * 4);
        float am = 0.f;
#pragma unroll
        for (int j = 0; j < 8; ++j)
            am = fmaxf(am, fmaxf(fmaxf(fabsf(v[j].x), fabsf(v[j].y)),
                                 fmaxf(fabsf(v[j].z), fabsf(v[j].w))));
        am = fmaxf(am, __shfl_xor(am, 1));
        am = fmaxf(am, __shfl_xor(am, 2));
        am = fmaxf(am, 1e-4f);
        float scale = am / FP8_MAX;     // exact reference scale (IEEE div)
        float inv   = FP8_MAX / am;     // one div/thread; q = v*inv
        unsigned int* dst = (unsigned int*)&As[ar][aq * 32];
#pragma unroll
        for (int j = 0; j < 4; ++j) {
            floatx2 a0 = fp8_qdq2(v[2*j].x   * inv, v[2*j].y   * inv);
            floatx2 a1 = fp8_qdq2(v[2*j].z   * inv, v[2*j].w   * inv);
            floatx2 a2 = fp8_qdq2(v[2*j+1].x * inv, v[2*j+1].y * inv);
            floatx2 a3 = fp8_qdq2(v[2*j+1].z * inv, v[2*j+1].w * inv);
            uint4 o;
            o.x = f2bf(a0[0] * scale) | (f2bf(a0[1] * scale) << 16);
            o.y = f2bf(a1[0] * scale) | (f2bf(a1[1] * scale) << 16);
            o.z = f2bf(a2[0] * scale) | (f2bf(a2[1] * scale) << 16);
            o.w = f2bf(a3[0] * scale) | (f2bf(a3[1] * scale) << 16);
            *reinterpret_cast<uint4*>(dst + j * 4) = o;
        }
        __syncthreads();

        // ---- MFMA over the two 64-k halves ----
#pragma unroll
        for (int h = 0; h < 2; ++h) {
            if (h) {
                // restage Bs for k half 1 (As untouched)
#pragma unroll
                for (int c = 0; c < 8; ++c) {
                    int chunk = wid * 8 + c;
                    int frow  = chunk * 8 + (lane >> 3);
                    async_copy16((char*)&Bs[0][0] + chunk * 1024,
                                 (const char*)(Wb + (size_t)frow * K + k0 + 64) + (lane & 7) * 16);
                }
                __syncthreads();
            }
#pragma unroll
            for (int ks = 0; ks < 2; ++ks) {
                int ksg = h * 2 + ks;   // global k-slice in As
                bf16x8 a[4], b[4];
#pragma unroll
                for (int i = 0; i < 4; ++i) {
                    a[i] = *reinterpret_cast<const bf16x8*>(
                        &As[i * 16 + (lane & 15)][ksg * 32 + (lane >> 4) * 8]);
                    b[i] = *reinterpret_cast<const bf16x8*>(
                        &Bs[wid * 64 + i * 16 + (lane & 15)][ks * 32 + (lane >> 4) * 8]);
                }
#pragma unroll
                for (int mi = 0; mi < 4; ++mi)
#pragma unroll
                    for (int ni = 0; ni < 4; ++ni)
                        acc[mi][ni] = __builtin_amdgcn_mfma_f32_16x16x32_bf16(
                            a[mi], b[ni], acc[mi][ni], 0, 0, 0);
            }
            __syncthreads();   // Bs (and, last iter, As) safe to overwrite
        }
    }

    // ---- epilogue: C/D layout col=lane&15, row=(lane>>4)*4+e ----
    int fcol = tN * BN + wid * 64 + (lane & 15);
    int mrow = tM * BM + ((lane >> 4) << 2);
#pragma unroll
    for (int ni = 0; ni < 4; ++ni) {
        int f = fcol + ni * 16;
        float bv = bias[f];
#pragma unroll
        for (int mi = 0; mi < 4; ++mi) {
            int m0 = mrow + mi * 16;
#pragma unroll
            for (int e = 0; e < 4; ++e)
                C[(size_t)(m0 + e) * N + f] = acc[mi][ni][e] + bv;
        }
    }
}

// ---------------------------------------------------------------------------
extern "C" void kernel_launch(void* const* d_in, const int* in_sizes, int n_in,
                              void* d_out, int out_size, void* d_ws, size_t ws_size,
                              hipStream_t stream) {
    const float* X    = (const float*)d_in[0];
    const float* W    = (const float*)d_in[1];
    const float* bias = (const float*)d_in[2];
    const int K = 512;
    const int M = in_sizes[0] / K;   // 65536

    __hip_bfloat16* Wt = (__hip_bfloat16*)d_ws;   // 512*512*2 = 512 KB

    wdq_kernel<<<dim3(512), dim3(128), 0, stream>>>(W, Wt);
    fused_gemm<<<dim3((M / BM) * (512 / BN)), dim3(256), 0, stream>>>(
        X, Wt, bias, (float*)d_out, M);
}